// Round 8
// baseline (201.704 us; speedup 1.0000x reference)
//
#include <hip/hip_runtime.h>
#include <hip/hip_fp16.h>

#define NN 8192
#define INF 256
#define OUTF 128
#define LOG2E 1.44269504088896340736f

typedef float f32x4 __attribute__((ext_vector_type(4)));
typedef float f32x16 __attribute__((ext_vector_type(16)));
typedef __fp16 h16x8 __attribute__((ext_vector_type(8)));
typedef __fp16 h16x4 __attribute__((ext_vector_type(4)));
typedef __fp16 h16x2 __attribute__((ext_vector_type(2)));
typedef int i32x4 __attribute__((ext_vector_type(4)));

__device__ __forceinline__ void gload_lds16(const void* g, void* l) {
  __builtin_amdgcn_global_load_lds(
      (const __attribute__((address_space(1))) unsigned int*)g,
      (__attribute__((address_space(3))) unsigned int*)l, 16, 0, 0);
}

// ---------------- KB: adj int32 -> u16 bitmask, ROW-MAJOR [row][j16] (8 MB).
__global__ __launch_bounds__(256) void kb_pack(const int* __restrict__ adj,
                                               unsigned short* __restrict__ adjb) {
  int gid = blockIdx.x * 256 + threadIdx.x;
#pragma unroll
  for (int it = 0; it < 8; ++it) {
    size_t c = (size_t)it * 524288 + gid;     // u16-chunk index, 4M total
    const int* p = adj + c * 16;
    i32x4 v0 = *(const i32x4*)(p);
    i32x4 v1 = *(const i32x4*)(p + 4);
    i32x4 v2 = *(const i32x4*)(p + 8);
    i32x4 v3 = *(const i32x4*)(p + 12);
    unsigned int b = 0;
#pragma unroll
    for (int k = 0; k < 4; ++k) {
      b |= (v0[k] != 0 ? 1u : 0u) << k;
      b |= (v1[k] != 0 ? 1u : 0u) << (4 + k);
      b |= (v2[k] != 0 ? 1u : 0u) << (8 + k);
      b |= (v3[k] != 0 ? 1u : 0u) << (12 + k);
    }
    adjb[c] = (unsigned short)b;
  }
}

// ---------------- K0: W (256x128 f32) -> WT_perm f16 (for K1's 32x32x16 MFMA)
__global__ __launch_bounds__(256) void k0_wt(const float* __restrict__ W1,
                                             const float* __restrict__ W2,
                                             __fp16* __restrict__ WT) {
  int m = blockIdx.x * 256 + threadIdx.x;  // 8192 chunks of 16B
  int h = m >> 12;
  int r = m & 4095;
  int c = r >> 5;
  int kb = (r >> 1) & 15;
  int hh = r & 1;
  const float* W = h ? W2 : W1;
  float v[8];
#pragma unroll
  for (int s = 0; s < 8; ++s) {
    int koff = 4 * hh + (s & 3) + 8 * (s >> 2);
    v[s] = W[(kb * 16 + koff) * OUTF + c];
  }
  union { h16x2 h2[4]; i32x4 q; } u;
  u.h2[0] = __builtin_amdgcn_cvt_pkrtz(v[0], v[1]);
  u.h2[1] = __builtin_amdgcn_cvt_pkrtz(v[2], v[3]);
  u.h2[2] = __builtin_amdgcn_cvt_pkrtz(v[4], v[5]);
  u.h2[3] = __builtin_amdgcn_cvt_pkrtz(v[6], v[7]);
  *(i32x4*)(WT + (size_t)h * 32768 + c * 256 + kb * 16 + hh * 8) = u.q;
}

// ---------------- K1: h = inp@W via MFMA; emits hT2 in 32x32x16 B-frag layout:
// [head][j16][nf4][lane64][slot8] f16; also src'/dst' scaled by log2e.
__global__ __launch_bounds__(128) void k1_h(
    const float* __restrict__ inp, const __fp16* __restrict__ WT,
    const float* __restrict__ a1, const float* __restrict__ a2,
    __fp16* __restrict__ hT2, float* __restrict__ S, float* __restrict__ D) {
  __shared__ __align__(16) float hl[2][32][136];
  int tid = threadIdx.x;
  int w = tid >> 6;           // wave = head
  int l = tid & 63;
  int lr = l & 31, g = l >> 5;
  int i0 = blockIdx.x * 32;
  const __fp16* WTh = WT + (size_t)w * 32768;
  f32x16 acc[4];
#pragma unroll
  for (int nf = 0; nf < 4; ++nf)
#pragma unroll
    for (int e = 0; e < 16; ++e) acc[nf][e] = 0.0f;
  const float* ip = inp + (size_t)(i0 + lr) * INF;
#pragma unroll
  for (int kb = 0; kb < 16; ++kb) {
    f32x4 q0 = *(const f32x4*)(ip + kb * 16 + 4 * g);
    f32x4 q1 = *(const f32x4*)(ip + kb * 16 + 8 + 4 * g);
    union { h16x2 h2[4]; h16x8 h8; } ua;
    ua.h2[0] = __builtin_amdgcn_cvt_pkrtz(q0[0], q0[1]);
    ua.h2[1] = __builtin_amdgcn_cvt_pkrtz(q0[2], q0[3]);
    ua.h2[2] = __builtin_amdgcn_cvt_pkrtz(q1[0], q1[1]);
    ua.h2[3] = __builtin_amdgcn_cvt_pkrtz(q1[2], q1[3]);
#pragma unroll
    for (int nf = 0; nf < 4; ++nf) {
      h16x8 b = *(const h16x8*)(WTh + (nf * 32 + lr) * 256 + kb * 16 + g * 8);
      acc[nf] = __builtin_amdgcn_mfma_f32_32x32x16_f16(ua.h8, b, acc[nf], 0, 0, 0);
    }
  }
#pragma unroll
  for (int nf = 0; nf < 4; ++nf)
#pragma unroll
    for (int r = 0; r < 16; ++r) {
      int row = (r & 3) + 8 * (r >> 2) + 4 * g;
      hl[w][row][nf * 32 + lr] = acc[nf][r];
    }
  __syncthreads();
  const float* av = w ? a2 : a1;
  float s = 0.f, d = 0.f;
#pragma unroll
  for (int cc = 0; cc < 64; cc += 4) {
    int c = g * 64 + cc;
    f32x4 hv = *(const f32x4*)&hl[w][lr][c];
    f32x4 as = *(const f32x4*)(av + c);
    f32x4 ad = *(const f32x4*)(av + 128 + c);
    s += hv[0] * as[0] + hv[1] * as[1] + hv[2] * as[2] + hv[3] * as[3];
    d += hv[0] * ad[0] + hv[1] * ad[1] + hv[2] * ad[2] + hv[3] * ad[3];
  }
  s += __shfl_xor(s, 32);
  d += __shfl_xor(d, 32);
  if (g == 0) {
    S[(size_t)w * NN + i0 + lr] = s * LOG2E;
    D[(size_t)w * NN + i0 + lr] = d * LOG2E;
  }
  // hT2 emission: per head, 2 j16-blocks x 256 chunks(16B) = 512; 64 lanes x 8 iters.
  __fp16* hTh = hT2 + (size_t)w * (NN * OUTF);
#pragma unroll
  for (int it = 0; it < 8; ++it) {
    int id = it * 64 + l;           // [0,512)
    int jb = id >> 8;
    int sub = id & 255;
    int nf = sub >> 6, lq = sub & 63;
    int lqr = lq & 31, lqg = lq >> 5;
    float v[8];
#pragma unroll
    for (int s2 = 0; s2 < 8; ++s2) {
      int kloc = 4 * lqg + (s2 & 3) + 8 * (s2 >> 2);   // MFMA k-map (A/B identical)
      v[s2] = hl[w][jb * 16 + kloc][nf * 32 + lqr];
    }
    union { h16x2 h2[4]; i32x4 q; } u2;
    u2.h2[0] = __builtin_amdgcn_cvt_pkrtz(v[0], v[1]);
    u2.h2[1] = __builtin_amdgcn_cvt_pkrtz(v[2], v[3]);
    u2.h2[2] = __builtin_amdgcn_cvt_pkrtz(v[4], v[5]);
    u2.h2[3] = __builtin_amdgcn_cvt_pkrtz(v[6], v[7]);
    *(i32x4*)(hTh + (size_t)((i0 >> 4) + jb) * 2048 + sub * 8) = u2.q;
  }
}

// ---------------- K1c: gmax' per head
__global__ __launch_bounds__(256) void k1c_gmax(const float* __restrict__ D,
                                                float* __restrict__ GM) {
  __shared__ float r1[256], r2[256];
  int t = threadIdx.x;
  float m1 = -1e30f, m2 = -1e30f;
  for (int i = t; i < NN; i += 256) {
    m1 = fmaxf(m1, D[i]);
    m2 = fmaxf(m2, D[NN + i]);
  }
  r1[t] = m1; r2[t] = m2;
  __syncthreads();
  for (int s = 128; s > 0; s >>= 1) {
    if (t < s) { r1[t] = fmaxf(r1[t], r1[t + s]); r2[t] = fmaxf(r2[t], r2[t + s]); }
    __syncthreads();
  }
  if (t == 0) { GM[0] = r1[0]; GM[1] = r2[0]; }
}

// ---------------- K2: bitmask softmax + PV, 32x32x16 MFMA.
// grid 512 = 64 rowblocks(BM=128) x 8 js; 8 waves = 2 heads x 4 rowgroups(32).
// LDS: hT dbuf 2x16KB + D window 8KB. Single raw barrier at loop top;
// stage issued before compute -> vmcnt(0) has a full compute phase of slack.
__global__ __launch_bounds__(512, 4) void k2_attn(
    const unsigned short* __restrict__ adjb, const __fp16* __restrict__ hT2,
    const float* __restrict__ S, const float* __restrict__ D,
    const float* __restrict__ GM, __fp16* __restrict__ NUM, float* __restrict__ DEN) {
  __shared__ __align__(16) char smem[40960];
  int tid = threadIdx.x;
  int w = tid >> 6;
  int l = tid & 63;
  int lr = l & 31, g2 = l >> 5;
  int h = w >> 2, rq = w & 3;
  int rb = blockIdx.x >> 3, js = blockIdx.x & 7;
  int i0 = rb * 128;
  int jwin = js * 1024, jw16 = js * 64;
  int row = i0 + rq * 32 + lr;
  float sf = S[(size_t)h * NN + row];
  float gm = GM[h];
  float v0 = sf + gm;
  float cneg = -fmaxf(v0, 0.2f * v0) - 1000.0f;
  float Ac = sf + cneg;          // max(t,0.2t)+cneg = max(Ac+dd, fma(0.2,dd,Bc))
  float Bc = 0.2f * sf + cneg;

  f32x16 acc[4];
#pragma unroll
  for (int nf = 0; nf < 4; ++nf)
#pragma unroll
    for (int e = 0; e < 16; ++e) acc[nf][e] = 0.0f;
  float dsum = 0.f;

  auto STAGE = [&](int jstep, int b) {
#pragma unroll
    for (int q = 0; q < 2; ++q) {
      int gi = q * 512 + tid;          // 16B-unit id in [0,1024)
      int seg = gi >> 8;               // kk*2 + hh
      int kk_l = seg >> 1, hh = seg & 1;
      const __fp16* gs = hT2 + (size_t)hh * (NN * OUTF) +
                         (size_t)(jw16 + jstep * 2 + kk_l) * 2048 + (gi & 255) * 8;
      gload_lds16(gs, smem + b * 16384 + gi * 16);
    }
  };

  // per-lane mask window: hold 8 u16 in regs, refresh every 4 jsteps
  const unsigned short* mrow = adjb + (size_t)row * 512 + jw16;
  i32x4 mreg = *(const i32x4*)(mrow);       // jsteps 0..3
  i32x4 mnext = *(const i32x4*)(mrow + 8);  // jsteps 4..7

  {  // D window -> LDS [2][1024] f32 at smem+32768 (linear dest = tid*16)
    int hh = tid >> 8, jj = tid & 255;
    gload_lds16(D + (size_t)hh * NN + jwin + jj * 4, smem + 32768 + tid * 16);
  }
  STAGE(0, 0);
  asm volatile("s_waitcnt vmcnt(0)" ::: "memory");
  __builtin_amdgcn_s_barrier();
  __builtin_amdgcn_sched_barrier(0);

  const float* DwH = (const float*)(smem + 32768) + h * 1024 + 4 * g2;

  for (int j4 = 0; j4 < 8; ++j4) {
#pragma unroll
    for (int u = 0; u < 4; ++u) {
      const int jstep = j4 * 4 + u;
      const int b = u & 1;             // == jstep & 1
      if (j4 + u) {                    // top-of-iter sync (skip first; prologue drained)
        asm volatile("s_waitcnt vmcnt(0)" ::: "memory");
        __builtin_amdgcn_s_barrier();
        __builtin_amdgcn_sched_barrier(0);
      }
      if (jstep < 31) STAGE(jstep + 1, b ^ 1);
      if (u == 0 && j4) {
        mreg = mnext;
        if (j4 < 7) mnext = *(const i32x4*)(mrow + (j4 + 1) * 8);
      }
      unsigned int dwm = (unsigned int)mreg[u];   // compile-time index (no scratch)
#pragma unroll
      for (int kk = 0; kk < 2; ++kk) {
        int kkg = jstep * 2 + kk;
        f32x4 d0 = *(const f32x4*)(DwH + kkg * 16);
        f32x4 d1 = *(const f32x4*)(DwH + kkg * 16 + 8);
        unsigned int bt = kk ? (dwm >> 16) : (dwm & 0xffffu);
        float pv[8];
#pragma unroll
        for (int s = 0; s < 8; ++s) {
          float dd = (s < 4) ? d0[s] : d1[s - 4];
          int kloc = 4 * g2 + (s & 3) + 8 * (s >> 2);
          float m1 = Ac + dd;
          float m2 = fmaf(0.2f, dd, Bc);
          float uu = fmaxf(m1, m2);
          float bf = (float)((bt >> kloc) & 1u);
          pv[s] = __builtin_amdgcn_exp2f(fmaf(bf, 1000.0f, uu));  // masked -> 0
        }
        dsum += ((pv[0] + pv[1]) + (pv[2] + pv[3])) + ((pv[4] + pv[5]) + (pv[6] + pv[7]));
        union { h16x2 h2[4]; h16x8 h8; } up;
        up.h2[0] = __builtin_amdgcn_cvt_pkrtz(pv[0], pv[1]);
        up.h2[1] = __builtin_amdgcn_cvt_pkrtz(pv[2], pv[3]);
        up.h2[2] = __builtin_amdgcn_cvt_pkrtz(pv[4], pv[5]);
        up.h2[3] = __builtin_amdgcn_cvt_pkrtz(pv[6], pv[7]);
        const char* lb = smem + b * 16384 + (kk * 2 + h) * 4096 + l * 16;
#pragma unroll
        for (int nf = 0; nf < 4; ++nf) {
          h16x8 Bf = *(const h16x8*)(lb + nf * 1024);
          acc[nf] = __builtin_amdgcn_mfma_f32_32x32x16_f16(up.h8, Bf, acc[nf], 0, 0, 0);
        }
      }
    }
  }

  // denom: lanes l and l+32 share a row
  dsum += __shfl_xor(dsum, 32);
  if (g2 == 0) DEN[(size_t)(js * 2 + h) * NN + row] = dsum;
  // C layout (32x32): col = lr, crow = (r&3)+8*(r>>2)+4*g2
  __fp16* nb = NUM + ((size_t)(js * 2 + h) * NN + i0 + rq * 32) * 128 + lr;
#pragma unroll
  for (int nf = 0; nf < 4; ++nf)
#pragma unroll
    for (int r = 0; r < 16; ++r) {
      int crow = (r & 3) + 8 * (r >> 2) + 4 * g2;
      nb[(size_t)crow * 128 + nf * 32] = (__fp16)acc[nf][r];
    }
}

// ---------------- K3: merge js partials, combine heads, ELU
__global__ __launch_bounds__(256) void k3_out(const __fp16* __restrict__ NUM,
                                              const float* __restrict__ DEN,
                                              float* __restrict__ out) {
  int gid = blockIdx.x * 256 + threadIdx.x;  // 262144
  int i = gid >> 5;
  int c4 = (gid & 31) * 4;
  f32x4 n1 = {0.f, 0.f, 0.f, 0.f}, n2 = {0.f, 0.f, 0.f, 0.f};
  float d1 = 0.f, d2 = 0.f;
#pragma unroll
  for (int js = 0; js < 8; ++js) {
    h16x4 a1v = *(const h16x4*)(NUM + ((size_t)(js * 2 + 0) * NN + i) * 128 + c4);
    h16x4 a2v = *(const h16x4*)(NUM + ((size_t)(js * 2 + 1) * NN + i) * 128 + c4);
#pragma unroll
    for (int e = 0; e < 4; ++e) { n1[e] += (float)a1v[e]; n2[e] += (float)a2v[e]; }
    d1 += DEN[(size_t)(js * 2 + 0) * NN + i];
    d2 += DEN[(size_t)(js * 2 + 1) * NN + i];
  }
  float r1 = 1.0f / d1, r2 = 0.5f / d2;
  f32x4 o;
#pragma unroll
  for (int e = 0; e < 4; ++e) {
    float x = n1[e] * r1 + n2[e] * r2;
    o[e] = x > 0.f ? x : (exp2f(x * LOG2E) - 1.0f);
  }
  *(f32x4*)(out + (size_t)i * 128 + c4) = o;
}

extern "C" void kernel_launch(void* const* d_in, const int* in_sizes, int n_in,
                              void* d_out, int out_size, void* d_ws, size_t ws_size,
                              hipStream_t stream) {
  const float* inp = (const float*)d_in[0];
  const int* adj = (const int*)d_in[1];
  const float* W1 = (const float*)d_in[2];
  const float* a1 = (const float*)d_in[3];
  const float* W2 = (const float*)d_in[4];
  const float* a2 = (const float*)d_in[5];
  float* out = (float*)d_out;
  char* ws = (char*)d_ws;
  // ws layout (~46.9 MB):
  __fp16* WT = (__fp16*)(ws);                              // 128 KB
  __fp16* hT2 = (__fp16*)(ws + 131072);                    // 4 MB
  float* S = (float*)(ws + 4325376);                       // 64 KB
  float* D = (float*)(ws + 4390912);                       // 64 KB
  float* GM = (float*)(ws + 4456448);                      // 256 B
  unsigned short* adjb = (unsigned short*)(ws + 4456704);  // 8 MB row-major
  __fp16* NUM = (__fp16*)(ws + 12845312);                  // 32 MB
  float* DEN = (float*)(ws + 46399744);                    // 512 KB

  kb_pack<<<dim3(2048), dim3(256), 0, stream>>>(adj, adjb);
  k0_wt<<<dim3(32), dim3(256), 0, stream>>>(W1, W2, WT);
  k1_h<<<dim3(256), dim3(128), 0, stream>>>(inp, WT, a1, a2, hT2, S, D);
  k1c_gmax<<<dim3(1), dim3(256), 0, stream>>>(D, GM);
  k2_attn<<<dim3(512), dim3(512), 0, stream>>>(adjb, hT2, S, D, GM, NUM, DEN);
  k3_out<<<dim3(1024), dim3(256), 0, stream>>>(NUM, DEN, out);
}

// Round 9
// 146.526 us; speedup vs baseline: 1.3766x; 1.3766x over previous
//
#include <hip/hip_runtime.h>
#include <hip/hip_fp16.h>

#define NN 8192
#define INF 256
#define OUTF 128
#define LOG2E 1.44269504088896340736f

typedef float f32x4 __attribute__((ext_vector_type(4)));
typedef float f32x16 __attribute__((ext_vector_type(16)));
typedef __fp16 h16x8 __attribute__((ext_vector_type(8)));
typedef __fp16 h16x4 __attribute__((ext_vector_type(4)));
typedef __fp16 h16x2 __attribute__((ext_vector_type(2)));
typedef int i32x4 __attribute__((ext_vector_type(4)));

__device__ __forceinline__ void gload_lds16(const void* g, void* l) {
  __builtin_amdgcn_global_load_lds(
      (const __attribute__((address_space(1))) unsigned int*)g,
      (__attribute__((address_space(3))) unsigned int*)l, 16, 0, 0);
}

// ---------------- KB: adj int32 -> u16 bitmask, ROW-MAJOR [row][j16] (8 MB).
__global__ __launch_bounds__(256) void kb_pack(const int* __restrict__ adj,
                                               unsigned short* __restrict__ adjb) {
  int gid = blockIdx.x * 256 + threadIdx.x;
#pragma unroll
  for (int it = 0; it < 8; ++it) {
    size_t c = (size_t)it * 524288 + gid;     // u16-chunk index, 4M total
    const int* p = adj + c * 16;
    i32x4 v0 = *(const i32x4*)(p);
    i32x4 v1 = *(const i32x4*)(p + 4);
    i32x4 v2 = *(const i32x4*)(p + 8);
    i32x4 v3 = *(const i32x4*)(p + 12);
    unsigned int b = 0;
#pragma unroll
    for (int k = 0; k < 4; ++k) {
      b |= (v0[k] != 0 ? 1u : 0u) << k;
      b |= (v1[k] != 0 ? 1u : 0u) << (4 + k);
      b |= (v2[k] != 0 ? 1u : 0u) << (8 + k);
      b |= (v3[k] != 0 ? 1u : 0u) << (12 + k);
    }
    adjb[c] = (unsigned short)b;
  }
}

// ---------------- K0: W (256x128 f32) -> WT_perm f16 (for K1's 32x32x16 MFMA)
__global__ __launch_bounds__(256) void k0_wt(const float* __restrict__ W1,
                                             const float* __restrict__ W2,
                                             __fp16* __restrict__ WT) {
  int m = blockIdx.x * 256 + threadIdx.x;  // 8192 chunks of 16B
  int h = m >> 12;
  int r = m & 4095;
  int c = r >> 5;
  int kb = (r >> 1) & 15;
  int hh = r & 1;
  const float* W = h ? W2 : W1;
  float v[8];
#pragma unroll
  for (int s = 0; s < 8; ++s) {
    int koff = 4 * hh + (s & 3) + 8 * (s >> 2);
    v[s] = W[(kb * 16 + koff) * OUTF + c];
  }
  union { h16x2 h2[4]; i32x4 q; } u;
  u.h2[0] = __builtin_amdgcn_cvt_pkrtz(v[0], v[1]);
  u.h2[1] = __builtin_amdgcn_cvt_pkrtz(v[2], v[3]);
  u.h2[2] = __builtin_amdgcn_cvt_pkrtz(v[4], v[5]);
  u.h2[3] = __builtin_amdgcn_cvt_pkrtz(v[6], v[7]);
  *(i32x4*)(WT + (size_t)h * 32768 + c * 256 + kb * 16 + hh * 8) = u.q;
}

// ---------------- K1: h = inp@W via MFMA; emits hT2 in 32x32x16 B-frag layout:
// [head][j16][nf4][lane64][slot8] f16; also src'/dst' scaled by log2e.
__global__ __launch_bounds__(128) void k1_h(
    const float* __restrict__ inp, const __fp16* __restrict__ WT,
    const float* __restrict__ a1, const float* __restrict__ a2,
    __fp16* __restrict__ hT2, float* __restrict__ S, float* __restrict__ D) {
  __shared__ __align__(16) float hl[2][32][136];
  int tid = threadIdx.x;
  int w = tid >> 6;           // wave = head
  int l = tid & 63;
  int lr = l & 31, g = l >> 5;
  int i0 = blockIdx.x * 32;
  const __fp16* WTh = WT + (size_t)w * 32768;
  f32x16 acc[4];
#pragma unroll
  for (int nf = 0; nf < 4; ++nf)
#pragma unroll
    for (int e = 0; e < 16; ++e) acc[nf][e] = 0.0f;
  const float* ip = inp + (size_t)(i0 + lr) * INF;
#pragma unroll
  for (int kb = 0; kb < 16; ++kb) {
    f32x4 q0 = *(const f32x4*)(ip + kb * 16 + 4 * g);
    f32x4 q1 = *(const f32x4*)(ip + kb * 16 + 8 + 4 * g);
    union { h16x2 h2[4]; h16x8 h8; } ua;
    ua.h2[0] = __builtin_amdgcn_cvt_pkrtz(q0[0], q0[1]);
    ua.h2[1] = __builtin_amdgcn_cvt_pkrtz(q0[2], q0[3]);
    ua.h2[2] = __builtin_amdgcn_cvt_pkrtz(q1[0], q1[1]);
    ua.h2[3] = __builtin_amdgcn_cvt_pkrtz(q1[2], q1[3]);
#pragma unroll
    for (int nf = 0; nf < 4; ++nf) {
      h16x8 b = *(const h16x8*)(WTh + (nf * 32 + lr) * 256 + kb * 16 + g * 8);
      acc[nf] = __builtin_amdgcn_mfma_f32_32x32x16_f16(ua.h8, b, acc[nf], 0, 0, 0);
    }
  }
#pragma unroll
  for (int nf = 0; nf < 4; ++nf)
#pragma unroll
    for (int r = 0; r < 16; ++r) {
      int row = (r & 3) + 8 * (r >> 2) + 4 * g;
      hl[w][row][nf * 32 + lr] = acc[nf][r];
    }
  __syncthreads();
  const float* av = w ? a2 : a1;
  float s = 0.f, d = 0.f;
#pragma unroll
  for (int cc = 0; cc < 64; cc += 4) {
    int c = g * 64 + cc;
    f32x4 hv = *(const f32x4*)&hl[w][lr][c];
    f32x4 as = *(const f32x4*)(av + c);
    f32x4 ad = *(const f32x4*)(av + 128 + c);
    s += hv[0] * as[0] + hv[1] * as[1] + hv[2] * as[2] + hv[3] * as[3];
    d += hv[0] * ad[0] + hv[1] * ad[1] + hv[2] * ad[2] + hv[3] * ad[3];
  }
  s += __shfl_xor(s, 32);
  d += __shfl_xor(d, 32);
  if (g == 0) {
    S[(size_t)w * NN + i0 + lr] = s * LOG2E;
    D[(size_t)w * NN + i0 + lr] = d * LOG2E;
  }
  // hT2 emission: per head, 2 j16-blocks x 256 chunks(16B) = 512; 64 lanes x 8 iters.
  __fp16* hTh = hT2 + (size_t)w * (NN * OUTF);
#pragma unroll
  for (int it = 0; it < 8; ++it) {
    int id = it * 64 + l;           // [0,512)
    int jb = id >> 8;
    int sub = id & 255;
    int nf = sub >> 6, lq = sub & 63;
    int lqr = lq & 31, lqg = lq >> 5;
    float v[8];
#pragma unroll
    for (int s2 = 0; s2 < 8; ++s2) {
      int kloc = 4 * lqg + (s2 & 3) + 8 * (s2 >> 2);   // MFMA k-map (A/B identical)
      v[s2] = hl[w][jb * 16 + kloc][nf * 32 + lqr];
    }
    union { h16x2 h2[4]; i32x4 q; } u2;
    u2.h2[0] = __builtin_amdgcn_cvt_pkrtz(v[0], v[1]);
    u2.h2[1] = __builtin_amdgcn_cvt_pkrtz(v[2], v[3]);
    u2.h2[2] = __builtin_amdgcn_cvt_pkrtz(v[4], v[5]);
    u2.h2[3] = __builtin_amdgcn_cvt_pkrtz(v[6], v[7]);
    *(i32x4*)(hTh + (size_t)((i0 >> 4) + jb) * 2048 + sub * 8) = u2.q;
  }
}

// ---------------- K1c: gmax' per head
__global__ __launch_bounds__(256) void k1c_gmax(const float* __restrict__ D,
                                                float* __restrict__ GM) {
  __shared__ float r1[256], r2[256];
  int t = threadIdx.x;
  float m1 = -1e30f, m2 = -1e30f;
  for (int i = t; i < NN; i += 256) {
    m1 = fmaxf(m1, D[i]);
    m2 = fmaxf(m2, D[NN + i]);
  }
  r1[t] = m1; r2[t] = m2;
  __syncthreads();
  for (int s = 128; s > 0; s >>= 1) {
    if (t < s) { r1[t] = fmaxf(r1[t], r1[t + s]); r2[t] = fmaxf(r2[t], r2[t + s]); }
    __syncthreads();
  }
  if (t == 0) { GM[0] = r1[0]; GM[1] = r2[0]; }
}

// ---------------- K2: bitmask softmax + PV, 32x32x16 MFMA, 64 rows/wave (2 A-frags)
// -> halves per-CU LDS B-frag read traffic (the r7/r8 bottleneck pipe).
// grid 512 = 64 rowblocks(BM=128) x 8 js; 4 waves = 2 heads x 1 rowgroup(64).
// 2 blocks/CU: block B computes while block A barriers. D stays GLOBAL (L1
// broadcast, vmem pipe) - r8 proved putting it in LDS hurts the LDS pipe.
__global__ __launch_bounds__(256, 2) void k2_attn(
    const unsigned short* __restrict__ adjb, const __fp16* __restrict__ hT2,
    const float* __restrict__ S, const float* __restrict__ D,
    const float* __restrict__ GM, __fp16* __restrict__ NUM, float* __restrict__ DEN) {
  __shared__ __align__(16) char smem[32768];  // 2 buf x (2 kk x 2 heads x 4KB)
  int tid = threadIdx.x;
  int w = tid >> 6;
  int l = tid & 63;
  int lr = l & 31, g2 = l >> 5;
  int h = w >> 1, rq = w & 1;
  int rb = blockIdx.x >> 3, js = blockIdx.x & 7;
  int i0 = rb * 128;
  int jwin = js * 1024, jw16 = js * 64;
  int base = i0 + rq * 64;
  int row0 = base + lr, row1 = base + 32 + lr;
  float gm = GM[h];
  float sf0 = S[(size_t)h * NN + row0];
  float sf1 = S[(size_t)h * NN + row1];
  float t0 = sf0 + gm, t1 = sf1 + gm;
  float cn0 = -fmaxf(t0, 0.2f * t0) - 1000.0f;
  float cn1 = -fmaxf(t1, 0.2f * t1) - 1000.0f;
  float Ac0 = sf0 + cn0, Bc0 = 0.2f * sf0 + cn0;  // max(t,.2t)+cn = max(Ac+dd, fma(.2,dd,Bc))
  float Ac1 = sf1 + cn1, Bc1 = 0.2f * sf1 + cn1;
  const float* Dh = D + (size_t)h * NN + jwin + 4 * g2;

  f32x16 acc[2][4];
#pragma unroll
  for (int f = 0; f < 2; ++f)
#pragma unroll
    for (int nf = 0; nf < 4; ++nf)
#pragma unroll
      for (int e = 0; e < 16; ++e) acc[f][nf][e] = 0.0f;
  float dsum0 = 0.f, dsum1 = 0.f;

  auto STAGE = [&](int jstep, int b) {
#pragma unroll
    for (int q = 0; q < 4; ++q) {          // q = kk_l*2 + hh
      int kk_l = q >> 1, hh = q & 1;
      const __fp16* gs = hT2 + (size_t)hh * (NN * OUTF) +
                         (size_t)(jw16 + jstep * 2 + kk_l) * 2048 + tid * 8;
      gload_lds16(gs, smem + b * 16384 + q * 4096 + tid * 16);
    }
  };

  // per-lane mask windows (2 rows), refresh every 4 jsteps
  const unsigned short* mrow0 = adjb + (size_t)row0 * 512 + jw16;
  const unsigned short* mrow1 = adjb + (size_t)row1 * 512 + jw16;
  i32x4 mreg0 = *(const i32x4*)(mrow0), mnext0 = *(const i32x4*)(mrow0 + 8);
  i32x4 mreg1 = *(const i32x4*)(mrow1), mnext1 = *(const i32x4*)(mrow1 + 8);

  const h16x2 ones = {(__fp16)1.0f, (__fp16)1.0f};

  STAGE(0, 0);
  __syncthreads();

  for (int j4 = 0; j4 < 8; ++j4) {
#pragma unroll
    for (int u = 0; u < 4; ++u) {
      const int jstep = j4 * 4 + u;
      const int b = jstep & 1;
      if (jstep < 31) STAGE(jstep + 1, b ^ 1);
      if (u == 0 && j4) {
        mreg0 = mnext0; mreg1 = mnext1;
        if (j4 < 7) {
          mnext0 = *(const i32x4*)(mrow0 + (j4 + 1) * 8);
          mnext1 = *(const i32x4*)(mrow1 + (j4 + 1) * 8);
        }
      }
      unsigned int dwm0 = (unsigned int)mreg0[u];   // compile-time index
      unsigned int dwm1 = (unsigned int)mreg1[u];
#pragma unroll
      for (int kk = 0; kk < 2; ++kk) {
        int kkg = jstep * 2 + kk;
        f32x4 d0 = *(const f32x4*)(Dh + kkg * 16);
        f32x4 d1 = *(const f32x4*)(Dh + kkg * 16 + 8);
        unsigned int bts[2] = {kk ? (dwm0 >> 16) : (dwm0 & 0xffffu),
                               kk ? (dwm1 >> 16) : (dwm1 & 0xffffu)};
        h16x8 up[2];
#pragma unroll
        for (int f = 0; f < 2; ++f) {
          float Af = f ? Ac1 : Ac0, Bf_ = f ? Bc1 : Bc0;
          unsigned int bt = bts[f];
          float pv[8];
#pragma unroll
          for (int s = 0; s < 8; ++s) {
            float dd = (s < 4) ? d0[s] : d1[s - 4];
            int kloc = 4 * g2 + (s & 3) + 8 * (s >> 2);
            float uu = fmaxf(Af + dd, fmaf(0.2f, dd, Bf_));
            float bfv = (float)((bt >> kloc) & 1u);
            pv[s] = __builtin_amdgcn_exp2f(fmaf(bfv, 1000.0f, uu));  // masked -> 0
          }
          union { h16x2 h2[4]; h16x8 h8; } uq;
          uq.h2[0] = __builtin_amdgcn_cvt_pkrtz(pv[0], pv[1]);
          uq.h2[1] = __builtin_amdgcn_cvt_pkrtz(pv[2], pv[3]);
          uq.h2[2] = __builtin_amdgcn_cvt_pkrtz(pv[4], pv[5]);
          uq.h2[3] = __builtin_amdgcn_cvt_pkrtz(pv[6], pv[7]);
          float ds = f ? dsum1 : dsum0;
#if __has_builtin(__builtin_amdgcn_fdot2)
          ds = __builtin_amdgcn_fdot2(uq.h2[0], ones, ds, false);
          ds = __builtin_amdgcn_fdot2(uq.h2[1], ones, ds, false);
          ds = __builtin_amdgcn_fdot2(uq.h2[2], ones, ds, false);
          ds = __builtin_amdgcn_fdot2(uq.h2[3], ones, ds, false);
#else
          ds += ((pv[0] + pv[1]) + (pv[2] + pv[3])) + ((pv[4] + pv[5]) + (pv[6] + pv[7]));
#endif
          if (f) dsum1 = ds; else dsum0 = ds;
          up[f] = uq.h8;
        }
        const char* lb = smem + b * 16384 + (kk * 2 + h) * 4096 + l * 16;
#pragma unroll
        for (int nf = 0; nf < 4; ++nf) {
          h16x8 Bf = *(const h16x8*)(lb + nf * 1024);
          acc[0][nf] = __builtin_amdgcn_mfma_f32_32x32x16_f16(up[0], Bf, acc[0][nf], 0, 0, 0);
          acc[1][nf] = __builtin_amdgcn_mfma_f32_32x32x16_f16(up[1], Bf, acc[1][nf], 0, 0, 0);
        }
      }
      __syncthreads();
    }
  }

  // denom: lanes l and l+32 share a row
  dsum0 += __shfl_xor(dsum0, 32);
  dsum1 += __shfl_xor(dsum1, 32);
  if (g2 == 0) {
    DEN[(size_t)(js * 2 + h) * NN + row0] = dsum0;
    DEN[(size_t)(js * 2 + h) * NN + row1] = dsum1;
  }
  // C layout (32x32): col = lr, crow = (r&3)+8*(r>>2)+4*g2
#pragma unroll
  for (int f = 0; f < 2; ++f) {
    __fp16* nb = NUM + ((size_t)(js * 2 + h) * NN + base + f * 32) * 128 + lr;
#pragma unroll
    for (int nf = 0; nf < 4; ++nf)
#pragma unroll
      for (int r = 0; r < 16; ++r) {
        int crow = (r & 3) + 8 * (r >> 2) + 4 * g2;
        nb[(size_t)crow * 128 + nf * 32] = (__fp16)acc[f][nf][r];
      }
  }
}

// ---------------- K3: merge js partials, combine heads, ELU
__global__ __launch_bounds__(256) void k3_out(const __fp16* __restrict__ NUM,
                                              const float* __restrict__ DEN,
                                              float* __restrict__ out) {
  int gid = blockIdx.x * 256 + threadIdx.x;  // 262144
  int i = gid >> 5;
  int c4 = (gid & 31) * 4;
  f32x4 n1 = {0.f, 0.f, 0.f, 0.f}, n2 = {0.f, 0.f, 0.f, 0.f};
  float d1 = 0.f, d2 = 0.f;
#pragma unroll
  for (int js = 0; js < 8; ++js) {
    h16x4 a1v = *(const h16x4*)(NUM + ((size_t)(js * 2 + 0) * NN + i) * 128 + c4);
    h16x4 a2v = *(const h16x4*)(NUM + ((size_t)(js * 2 + 1) * NN + i) * 128 + c4);
#pragma unroll
    for (int e = 0; e < 4; ++e) { n1[e] += (float)a1v[e]; n2[e] += (float)a2v[e]; }
    d1 += DEN[(size_t)(js * 2 + 0) * NN + i];
    d2 += DEN[(size_t)(js * 2 + 1) * NN + i];
  }
  float r1 = 1.0f / d1, r2 = 0.5f / d2;
  f32x4 o;
#pragma unroll
  for (int e = 0; e < 4; ++e) {
    float x = n1[e] * r1 + n2[e] * r2;
    o[e] = x > 0.f ? x : (exp2f(x * LOG2E) - 1.0f);
  }
  *(f32x4*)(out + (size_t)i * 128 + c4) = o;
}

extern "C" void kernel_launch(void* const* d_in, const int* in_sizes, int n_in,
                              void* d_out, int out_size, void* d_ws, size_t ws_size,
                              hipStream_t stream) {
  const float* inp = (const float*)d_in[0];
  const int* adj = (const int*)d_in[1];
  const float* W1 = (const float*)d_in[2];
  const float* a1 = (const float*)d_in[3];
  const float* W2 = (const float*)d_in[4];
  const float* a2 = (const float*)d_in[5];
  float* out = (float*)d_out;
  char* ws = (char*)d_ws;
  // ws layout (~46.9 MB):
  __fp16* WT = (__fp16*)(ws);                              // 128 KB
  __fp16* hT2 = (__fp16*)(ws + 131072);                    // 4 MB
  float* S = (float*)(ws + 4325376);                       // 64 KB
  float* D = (float*)(ws + 4390912);                       // 64 KB
  float* GM = (float*)(ws + 4456448);                      // 256 B
  unsigned short* adjb = (unsigned short*)(ws + 4456704);  // 8 MB row-major
  __fp16* NUM = (__fp16*)(ws + 12845312);                  // 32 MB
  float* DEN = (float*)(ws + 46399744);                    // 512 KB

  kb_pack<<<dim3(2048), dim3(256), 0, stream>>>(adj, adjb);
  k0_wt<<<dim3(32), dim3(256), 0, stream>>>(W1, W2, WT);
  k1_h<<<dim3(256), dim3(128), 0, stream>>>(inp, WT, a1, a2, hT2, S, D);
  k1c_gmax<<<dim3(1), dim3(256), 0, stream>>>(D, GM);
  k2_attn<<<dim3(512), dim3(256), 0, stream>>>(adjb, hT2, S, D, GM, NUM, DEN);
  k3_out<<<dim3(1024), dim3(256), 0, stream>>>(NUM, DEN, out);
}

// Round 10
// 136.758 us; speedup vs baseline: 1.4749x; 1.0714x over previous
//
#include <hip/hip_runtime.h>
#include <hip/hip_fp16.h>

#define NN 8192
#define INF 256
#define OUTF 128
#define LOG2E 1.44269504088896340736f

typedef float f32x4 __attribute__((ext_vector_type(4)));
typedef float f32x16 __attribute__((ext_vector_type(16)));
typedef __fp16 h16x8 __attribute__((ext_vector_type(8)));
typedef __fp16 h16x4 __attribute__((ext_vector_type(4)));
typedef __fp16 h16x2 __attribute__((ext_vector_type(2)));
typedef int i32x4 __attribute__((ext_vector_type(4)));

__device__ __forceinline__ void gload_lds16(const void* g, void* l) {
  __builtin_amdgcn_global_load_lds(
      (const __attribute__((address_space(1))) unsigned int*)g,
      (__attribute__((address_space(3))) unsigned int*)l, 16, 0, 0);
}

// order-preserving float->uint encoding (for atomicMax-based global max)
__device__ __forceinline__ unsigned encf(float f) {
  int b = __float_as_int(f);
  return b >= 0 ? ((unsigned)b | 0x80000000u) : ~(unsigned)b;
}
__device__ __forceinline__ float decf(unsigned u) {
  int b = (u & 0x80000000u) ? (int)(u & 0x7FFFFFFFu) : ~(int)u;
  return __int_as_float(b);
}

// ---------------- KB: adj int32 -> u16 bitmask, ROW-MAJOR [row][j16] (8 MB).
__global__ __launch_bounds__(256) void kb_pack(const int* __restrict__ adj,
                                               unsigned short* __restrict__ adjb) {
  int gid = blockIdx.x * 256 + threadIdx.x;
#pragma unroll
  for (int it = 0; it < 8; ++it) {
    size_t c = (size_t)it * 524288 + gid;     // u16-chunk index, 4M total
    const int* p = adj + c * 16;
    i32x4 v0 = *(const i32x4*)(p);
    i32x4 v1 = *(const i32x4*)(p + 4);
    i32x4 v2 = *(const i32x4*)(p + 8);
    i32x4 v3 = *(const i32x4*)(p + 12);
    unsigned int b = 0;
#pragma unroll
    for (int k = 0; k < 4; ++k) {
      b |= (v0[k] != 0 ? 1u : 0u) << k;
      b |= (v1[k] != 0 ? 1u : 0u) << (4 + k);
      b |= (v2[k] != 0 ? 1u : 0u) << (8 + k);
      b |= (v3[k] != 0 ? 1u : 0u) << (12 + k);
    }
    adjb[c] = (unsigned short)b;
  }
}

// ---------------- K0: W -> WT_perm f16; also zeroes GMu (runs before k1)
__global__ __launch_bounds__(256) void k0_wt(const float* __restrict__ W1,
                                             const float* __restrict__ W2,
                                             __fp16* __restrict__ WT,
                                             unsigned* __restrict__ GMu) {
  if (blockIdx.x == 0 && threadIdx.x < 2) GMu[threadIdx.x] = 0u;
  int m = blockIdx.x * 256 + threadIdx.x;  // 8192 chunks of 16B
  int h = m >> 12;
  int r = m & 4095;
  int c = r >> 5;
  int kb = (r >> 1) & 15;
  int hh = r & 1;
  const float* W = h ? W2 : W1;
  float v[8];
#pragma unroll
  for (int s = 0; s < 8; ++s) {
    int koff = 4 * hh + (s & 3) + 8 * (s >> 2);
    v[s] = W[(kb * 16 + koff) * OUTF + c];
  }
  union { h16x2 h2[4]; i32x4 q; } u;
  u.h2[0] = __builtin_amdgcn_cvt_pkrtz(v[0], v[1]);
  u.h2[1] = __builtin_amdgcn_cvt_pkrtz(v[2], v[3]);
  u.h2[2] = __builtin_amdgcn_cvt_pkrtz(v[4], v[5]);
  u.h2[3] = __builtin_amdgcn_cvt_pkrtz(v[6], v[7]);
  *(i32x4*)(WT + (size_t)h * 32768 + c * 256 + kb * 16 + hh * 8) = u.q;
}

// ---------------- K1: h = inp@W via MFMA; emits hT2 (32x32x16 B-frag layout),
// src'/dst' scaled by log2e; atomicMax global dst'-max (replaces k1c).
__global__ __launch_bounds__(128) void k1_h(
    const float* __restrict__ inp, const __fp16* __restrict__ WT,
    const float* __restrict__ a1, const float* __restrict__ a2,
    __fp16* __restrict__ hT2, float* __restrict__ S, float* __restrict__ D,
    unsigned* __restrict__ GMu) {
  __shared__ __align__(16) float hl[2][32][136];
  int tid = threadIdx.x;
  int w = tid >> 6;           // wave = head
  int l = tid & 63;
  int lr = l & 31, g = l >> 5;
  int i0 = blockIdx.x * 32;
  const __fp16* WTh = WT + (size_t)w * 32768;
  f32x16 acc[4];
#pragma unroll
  for (int nf = 0; nf < 4; ++nf)
#pragma unroll
    for (int e = 0; e < 16; ++e) acc[nf][e] = 0.0f;
  const float* ip = inp + (size_t)(i0 + lr) * INF;
#pragma unroll
  for (int kb = 0; kb < 16; ++kb) {
    f32x4 q0 = *(const f32x4*)(ip + kb * 16 + 4 * g);
    f32x4 q1 = *(const f32x4*)(ip + kb * 16 + 8 + 4 * g);
    union { h16x2 h2[4]; h16x8 h8; } ua;
    ua.h2[0] = __builtin_amdgcn_cvt_pkrtz(q0[0], q0[1]);
    ua.h2[1] = __builtin_amdgcn_cvt_pkrtz(q0[2], q0[3]);
    ua.h2[2] = __builtin_amdgcn_cvt_pkrtz(q1[0], q1[1]);
    ua.h2[3] = __builtin_amdgcn_cvt_pkrtz(q1[2], q1[3]);
#pragma unroll
    for (int nf = 0; nf < 4; ++nf) {
      h16x8 b = *(const h16x8*)(WTh + (nf * 32 + lr) * 256 + kb * 16 + g * 8);
      acc[nf] = __builtin_amdgcn_mfma_f32_32x32x16_f16(ua.h8, b, acc[nf], 0, 0, 0);
    }
  }
#pragma unroll
  for (int nf = 0; nf < 4; ++nf)
#pragma unroll
    for (int r = 0; r < 16; ++r) {
      int row = (r & 3) + 8 * (r >> 2) + 4 * g;
      hl[w][row][nf * 32 + lr] = acc[nf][r];
    }
  __syncthreads();
  const float* av = w ? a2 : a1;
  float s = 0.f, d = 0.f;
#pragma unroll
  for (int cc = 0; cc < 64; cc += 4) {
    int c = g * 64 + cc;
    f32x4 hv = *(const f32x4*)&hl[w][lr][c];
    f32x4 as = *(const f32x4*)(av + c);
    f32x4 ad = *(const f32x4*)(av + 128 + c);
    s += hv[0] * as[0] + hv[1] * as[1] + hv[2] * as[2] + hv[3] * as[3];
    d += hv[0] * ad[0] + hv[1] * ad[1] + hv[2] * ad[2] + hv[3] * ad[3];
  }
  s += __shfl_xor(s, 32);
  d += __shfl_xor(d, 32);
  float dl = d * LOG2E;
  if (g == 0) {
    S[(size_t)w * NN + i0 + lr] = s * LOG2E;
    D[(size_t)w * NN + i0 + lr] = dl;
  }
  // global dst'-max via wave reduce + 1 atomic per wave (replaces k1c kernel)
  float dmax = dl;
#pragma unroll
  for (int off = 1; off < 32; off <<= 1) dmax = fmaxf(dmax, __shfl_xor(dmax, off));
  if (l == 0) atomicMax(GMu + w, encf(dmax));
  // hT2 emission: per head, 2 j16-blocks x 256 chunks(16B) = 512; 64 lanes x 8 iters.
  __fp16* hTh = hT2 + (size_t)w * (NN * OUTF);
#pragma unroll
  for (int it = 0; it < 8; ++it) {
    int id = it * 64 + l;           // [0,512)
    int jb = id >> 8;
    int sub = id & 255;
    int nf = sub >> 6, lq = sub & 63;
    int lqr = lq & 31, lqg = lq >> 5;
    float v[8];
#pragma unroll
    for (int s2 = 0; s2 < 8; ++s2) {
      int kloc = 4 * lqg + (s2 & 3) + 8 * (s2 >> 2);   // MFMA k-map (A/B identical)
      v[s2] = hl[w][jb * 16 + kloc][nf * 32 + lqr];
    }
    union { h16x2 h2[4]; i32x4 q; } u2;
    u2.h2[0] = __builtin_amdgcn_cvt_pkrtz(v[0], v[1]);
    u2.h2[1] = __builtin_amdgcn_cvt_pkrtz(v[2], v[3]);
    u2.h2[2] = __builtin_amdgcn_cvt_pkrtz(v[4], v[5]);
    u2.h2[3] = __builtin_amdgcn_cvt_pkrtz(v[6], v[7]);
    *(i32x4*)(hTh + (size_t)((i0 >> 4) + jb) * 2048 + sub * 8) = u2.q;
  }
}

// ---------------- K2: bitmask softmax + PV, 32x32x16 MFMA, 64 rows/wave.
// PING-PONG: softmax(j+1) (VALU, global D + reg masks only) overlaps MFMA(j)
// (LDS reads + MFMA pipe) within each wave -> pipes co-issue instead of serial.
__global__ __launch_bounds__(256, 2) void k2_attn(
    const unsigned short* __restrict__ adjb, const __fp16* __restrict__ hT2,
    const float* __restrict__ S, const float* __restrict__ D,
    const unsigned* __restrict__ GMu, __fp16* __restrict__ NUM,
    float* __restrict__ DEN) {
  __shared__ __align__(16) char smem[32768];  // 2 buf x (2 kk x 2 heads x 4KB)
  int tid = threadIdx.x;
  int w = tid >> 6;
  int l = tid & 63;
  int lr = l & 31, g2 = l >> 5;
  int h = w >> 1, rq = w & 1;
  int rb = blockIdx.x >> 3, js = blockIdx.x & 7;
  int i0 = rb * 128;
  int jwin = js * 1024, jw16 = js * 64;
  int base = i0 + rq * 64;
  int row0 = base + lr, row1 = base + 32 + lr;
  float gm = decf(GMu[h]);
  float sf0 = S[(size_t)h * NN + row0];
  float sf1 = S[(size_t)h * NN + row1];
  float t0 = sf0 + gm, t1 = sf1 + gm;
  float cn0 = -fmaxf(t0, 0.2f * t0) - 1000.0f;
  float cn1 = -fmaxf(t1, 0.2f * t1) - 1000.0f;
  float Ac0 = sf0 + cn0, Bc0 = 0.2f * sf0 + cn0;
  float Ac1 = sf1 + cn1, Bc1 = 0.2f * sf1 + cn1;
  const float* Dh = D + (size_t)h * NN + jwin + 4 * g2;

  f32x16 acc[2][4];
#pragma unroll
  for (int f = 0; f < 2; ++f)
#pragma unroll
    for (int nf = 0; nf < 4; ++nf)
#pragma unroll
      for (int e = 0; e < 16; ++e) acc[f][nf][e] = 0.0f;
  float dsum0 = 0.f, dsum1 = 0.f;

  auto STAGE = [&](int jstep, int b) {
#pragma unroll
    for (int q = 0; q < 4; ++q) {          // q = kk_l*2 + hh
      int kk_l = q >> 1, hh = q & 1;
      const __fp16* gs = hT2 + (size_t)hh * (NN * OUTF) +
                         (size_t)(jw16 + jstep * 2 + kk_l) * 2048 + tid * 8;
      gload_lds16(gs, smem + b * 16384 + q * 4096 + tid * 16);
    }
  };

  const unsigned short* mrow0 = adjb + (size_t)row0 * 512 + jw16;
  const unsigned short* mrow1 = adjb + (size_t)row1 * 512 + jw16;
  i32x4 mreg0 = *(const i32x4*)(mrow0), mnext0 = *(const i32x4*)(mrow0 + 8);
  i32x4 mreg1 = *(const i32x4*)(mrow1), mnext1 = *(const i32x4*)(mrow1 + 8);

  const h16x2 ones = {(__fp16)1.0f, (__fp16)1.0f};
  h16x8 P[2][2], Pn[2][2];   // [f][kk], compile-time indexed only

  // softmax for jstep jn -> Pn, dsum. Depends only on D (global) + mask words.
  auto SOFTMAX = [&](int jn, unsigned dwm0, unsigned dwm1) {
#pragma unroll
    for (int kk = 0; kk < 2; ++kk) {
      int kkg = jn * 2 + kk;
      f32x4 d0 = *(const f32x4*)(Dh + kkg * 16);
      f32x4 d1 = *(const f32x4*)(Dh + kkg * 16 + 8);
      unsigned bts[2] = {kk ? (dwm0 >> 16) : (dwm0 & 0xffffu),
                         kk ? (dwm1 >> 16) : (dwm1 & 0xffffu)};
#pragma unroll
      for (int f = 0; f < 2; ++f) {
        float Af = f ? Ac1 : Ac0, Bf_ = f ? Bc1 : Bc0;
        unsigned bt = bts[f];
        float pv[8];
#pragma unroll
        for (int s = 0; s < 8; ++s) {
          float dd = (s < 4) ? d0[s] : d1[s - 4];
          int kloc = 4 * g2 + (s & 3) + 8 * (s >> 2);
          float uu = fmaxf(Af + dd, fmaf(0.2f, dd, Bf_));
          float bfv = (float)((bt >> kloc) & 1u);
          pv[s] = __builtin_amdgcn_exp2f(fmaf(bfv, 1000.0f, uu));  // masked -> 0
        }
        union { h16x2 h2[4]; h16x8 h8; } uq;
        uq.h2[0] = __builtin_amdgcn_cvt_pkrtz(pv[0], pv[1]);
        uq.h2[1] = __builtin_amdgcn_cvt_pkrtz(pv[2], pv[3]);
        uq.h2[2] = __builtin_amdgcn_cvt_pkrtz(pv[4], pv[5]);
        uq.h2[3] = __builtin_amdgcn_cvt_pkrtz(pv[6], pv[7]);
        float ds = f ? dsum1 : dsum0;
#if __has_builtin(__builtin_amdgcn_fdot2)
        ds = __builtin_amdgcn_fdot2(uq.h2[0], ones, ds, false);
        ds = __builtin_amdgcn_fdot2(uq.h2[1], ones, ds, false);
        ds = __builtin_amdgcn_fdot2(uq.h2[2], ones, ds, false);
        ds = __builtin_amdgcn_fdot2(uq.h2[3], ones, ds, false);
#else
        ds += ((pv[0] + pv[1]) + (pv[2] + pv[3])) + ((pv[4] + pv[5]) + (pv[6] + pv[7]));
#endif
        if (f) dsum1 = ds; else dsum0 = ds;
        Pn[f][kk] = uq.h8;
      }
    }
  };

  auto MFMA_STEP = [&](int b) {
#pragma unroll
    for (int kk = 0; kk < 2; ++kk) {
      const char* lb = smem + b * 16384 + (kk * 2 + h) * 4096 + l * 16;
#pragma unroll
      for (int nf = 0; nf < 4; ++nf) {
        h16x8 Bf = *(const h16x8*)(lb + nf * 1024);
        acc[0][nf] = __builtin_amdgcn_mfma_f32_32x32x16_f16(P[0][kk], Bf, acc[0][nf], 0, 0, 0);
        acc[1][nf] = __builtin_amdgcn_mfma_f32_32x32x16_f16(P[1][kk], Bf, acc[1][nf], 0, 0, 0);
      }
    }
  };

  // prologue: stage(0), softmax(0)
  STAGE(0, 0);
  SOFTMAX(0, (unsigned)mreg0[0], (unsigned)mreg1[0]);
#pragma unroll
  for (int f = 0; f < 2; ++f)
#pragma unroll
    for (int kk = 0; kk < 2; ++kk) P[f][kk] = Pn[f][kk];
  __syncthreads();

  for (int j4 = 0; j4 < 8; ++j4) {
#pragma unroll
    for (int u = 0; u < 4; ++u) {
      const int jstep = j4 * 4 + u;
      const int b = jstep & 1;
      if (jstep < 31) STAGE(jstep + 1, b ^ 1);
      if (u == 3) {  // shift mask window before softmax(jstep+1) needs group j4+1
        mreg0 = mnext0; mreg1 = mnext1;
        if (j4 < 6) {
          mnext0 = *(const i32x4*)(mrow0 + (j4 + 2) * 8);
          mnext1 = *(const i32x4*)(mrow1 + (j4 + 2) * 8);
        }
      }
      if (jstep < 31) {
        const int un = (u + 1) & 3;
        SOFTMAX(jstep + 1, (unsigned)mreg0[un], (unsigned)mreg1[un]);
      }
      MFMA_STEP(b);
      if (jstep < 31) {
#pragma unroll
        for (int f = 0; f < 2; ++f)
#pragma unroll
          for (int kk = 0; kk < 2; ++kk) P[f][kk] = Pn[f][kk];
      }
      __syncthreads();
    }
  }

  // denom: lanes l and l+32 share a row
  dsum0 += __shfl_xor(dsum0, 32);
  dsum1 += __shfl_xor(dsum1, 32);
  if (g2 == 0) {
    DEN[(size_t)(js * 2 + h) * NN + row0] = dsum0;
    DEN[(size_t)(js * 2 + h) * NN + row1] = dsum1;
  }
  // C layout (32x32): col = lr, crow = (r&3)+8*(r>>2)+4*g2
#pragma unroll
  for (int f = 0; f < 2; ++f) {
    __fp16* nb = NUM + ((size_t)(js * 2 + h) * NN + base + f * 32) * 128 + lr;
#pragma unroll
    for (int nf = 0; nf < 4; ++nf)
#pragma unroll
      for (int r = 0; r < 16; ++r) {
        int crow = (r & 3) + 8 * (r >> 2) + 4 * g2;
        nb[(size_t)crow * 128 + nf * 32] = (__fp16)acc[f][nf][r];
      }
  }
}

// ---------------- K3: merge js partials, combine heads, ELU
__global__ __launch_bounds__(256) void k3_out(const __fp16* __restrict__ NUM,
                                              const float* __restrict__ DEN,
                                              float* __restrict__ out) {
  int gid = blockIdx.x * 256 + threadIdx.x;  // 262144
  int i = gid >> 5;
  int c4 = (gid & 31) * 4;
  f32x4 n1 = {0.f, 0.f, 0.f, 0.f}, n2 = {0.f, 0.f, 0.f, 0.f};
  float d1 = 0.f, d2 = 0.f;
#pragma unroll
  for (int js = 0; js < 8; ++js) {
    h16x4 a1v = *(const h16x4*)(NUM + ((size_t)(js * 2 + 0) * NN + i) * 128 + c4);
    h16x4 a2v = *(const h16x4*)(NUM + ((size_t)(js * 2 + 1) * NN + i) * 128 + c4);
#pragma unroll
    for (int e = 0; e < 4; ++e) { n1[e] += (float)a1v[e]; n2[e] += (float)a2v[e]; }
    d1 += DEN[(size_t)(js * 2 + 0) * NN + i];
    d2 += DEN[(size_t)(js * 2 + 1) * NN + i];
  }
  float r1 = 1.0f / d1, r2 = 0.5f / d2;
  f32x4 o;
#pragma unroll
  for (int e = 0; e < 4; ++e) {
    float x = n1[e] * r1 + n2[e] * r2;
    o[e] = x > 0.f ? x : (exp2f(x * LOG2E) - 1.0f);
  }
  *(f32x4*)(out + (size_t)i * 128 + c4) = o;
}

extern "C" void kernel_launch(void* const* d_in, const int* in_sizes, int n_in,
                              void* d_out, int out_size, void* d_ws, size_t ws_size,
                              hipStream_t stream) {
  const float* inp = (const float*)d_in[0];
  const int* adj = (const int*)d_in[1];
  const float* W1 = (const float*)d_in[2];
  const float* a1 = (const float*)d_in[3];
  const float* W2 = (const float*)d_in[4];
  const float* a2 = (const float*)d_in[5];
  float* out = (float*)d_out;
  char* ws = (char*)d_ws;
  // ws layout (~46.9 MB):
  __fp16* WT = (__fp16*)(ws);                              // 128 KB
  __fp16* hT2 = (__fp16*)(ws + 131072);                    // 4 MB
  float* S = (float*)(ws + 4325376);                       // 64 KB
  float* D = (float*)(ws + 4390912);                       // 64 KB
  unsigned* GMu = (unsigned*)(ws + 4456448);               // 256 B
  unsigned short* adjb = (unsigned short*)(ws + 4456704);  // 8 MB row-major
  __fp16* NUM = (__fp16*)(ws + 12845312);                  // 32 MB
  float* DEN = (float*)(ws + 46399744);                    // 512 KB

  kb_pack<<<dim3(2048), dim3(256), 0, stream>>>(adj, adjb);
  k0_wt<<<dim3(32), dim3(256), 0, stream>>>(W1, W2, WT, GMu);
  k1_h<<<dim3(256), dim3(128), 0, stream>>>(inp, WT, a1, a2, hT2, S, D, GMu);
  k2_attn<<<dim3(512), dim3(256), 0, stream>>>(adjb, hT2, S, D, GMu, NUM, DEN);
  k3_out<<<dim3(1024), dim3(256), 0, stream>>>(NUM, DEN, out);
}